// Round 5
// baseline (327.398 us; speedup 1.0000x reference)
//
#include <hip/hip_runtime.h>
#include <stdint.h>

// x (16,256,64,64) fp32; 32 groups; 8 heads; head dim 32. All I/O fp32.
// Intermediates bf16 in d_ws. GEMMs: bf16 MFMA 16x16x32, BK=64, swizzled
// coalesced global_load_lds staging, LDS-staged coalesced epilogue.
// Softmax folded into att: att = diag(1/l) * sum_n exp(k) v  (no max-sub; |k|<~6).
#define BATCH 16
#define CCH   256
#define NSP   4096
#define QKV_M 768

typedef unsigned short u16;
typedef short  short8 __attribute__((ext_vector_type(8)));   // 8 bf16 (4 VGPRs)
typedef float  f32x4  __attribute__((ext_vector_type(4)));

__device__ __forceinline__ float bf2f(u16 h) {
  union { unsigned int u; float f; } x; x.u = ((unsigned int)h) << 16; return x.f;
}
__device__ __forceinline__ u16 f2bf(float f) {
  union { float f; unsigned int u; } x; x.f = f;
  unsigned int r = 0x7fffu + ((x.u >> 16) & 1u);
  return (u16)((x.u + r) >> 16);
}

#define GLB(p) ((__attribute__((address_space(1))) void*)(p))
#define LDSP(p) ((__attribute__((address_space(3))) void*)(p))

// ------------------------------------------------ weights fp32 -> bf16
__global__ __launch_bounds__(256) void convw_kernel(const float* __restrict__ wq,
                                                    const float* __restrict__ wp,
                                                    u16* __restrict__ dst) {
  const int i = (blockIdx.x * 256 + threadIdx.x) * 4;
  float4 v = (i < 196608) ? *(const float4*)(wq + i)
                          : *(const float4*)(wp + (i - 196608));
  ushort4 o;
  o.x = f2bf(v.x); o.y = f2bf(v.y); o.z = f2bf(v.z); o.w = f2bf(v.w);
  *(ushort4*)(dst + i) = o;
}

// ------------------------------------------------ GroupNorm stats (+ zero att accum)
__global__ __launch_bounds__(256) void gn_stats(const float* __restrict__ x,
                                                float2* __restrict__ stats,
                                                float* __restrict__ att4) {
  const int blk = blockIdx.x;
  const int tid = threadIdx.x;
  // zero att accumulator: 128 heads * 1056 floats = 512 blocks * 264
  {
    float* az = att4 + (size_t)blk * 264;
    for (int i = tid; i < 264; i += 256) az[i] = 0.f;
  }
  const float4* xv = (const float4*)(x + (size_t)blk * 32768);
  float s = 0.f, ss = 0.f;
  for (int i = tid; i < 8192; i += 256) {
    float4 u = xv[i];
    s  += u.x + u.y + u.z + u.w;
    ss += u.x * u.x + u.y * u.y + u.z * u.z + u.w * u.w;
  }
#pragma unroll
  for (int off = 32; off > 0; off >>= 1) {
    s  += __shfl_down(s, off);
    ss += __shfl_down(ss, off);
  }
  __shared__ float red[8];
  const int wave = tid >> 6, lane = tid & 63;
  if (lane == 0) { red[wave * 2] = s; red[wave * 2 + 1] = ss; }
  __syncthreads();
  if (tid == 0) {
    const float S  = red[0] + red[2] + red[4] + red[6];
    const float SS = red[1] + red[3] + red[5] + red[7];
    const float mean = S * (1.f / 32768.f);
    const float var  = SS * (1.f / 32768.f) - mean * mean;
    stats[blk] = make_float2(mean, rsqrtf(var + 1e-5f));
  }
}

// ------------------------------------------------ GN apply + transpose
__global__ __launch_bounds__(256) void gn_apply_t(const float* __restrict__ x,
                                                  const float* __restrict__ gw,
                                                  const float* __restrict__ gb,
                                                  const float2* __restrict__ stats,
                                                  u16* __restrict__ xnT) {
  __shared__ u16 ls[64][72];                    // [c][n], pad 72
  const int b = blockIdx.z, c0 = blockIdx.y * 64, n0 = blockIdx.x * 64;
  const int tid = threadIdx.x;
#pragma unroll
  for (int r = 0; r < 4; ++r) {
    const int cc = (tid >> 4) + r * 16;
    const int nn = (tid & 15) * 4;
    const int c = c0 + cc;
    const float2 st = stats[b * 32 + (c >> 3)];
    const float wv = gw[c] * st.y;
    const float bv = gb[c] - st.x * wv;
    float4 u = *(const float4*)(x + ((size_t)b * CCH + c) * NSP + n0 + nn);
    ushort4 o;
    o.x = f2bf(u.x * wv + bv);
    o.y = f2bf(u.y * wv + bv);
    o.z = f2bf(u.z * wv + bv);
    o.w = f2bf(u.w * wv + bv);
    *(ushort4*)&ls[cc][nn] = o;
  }
  __syncthreads();
#pragma unroll
  for (int p = 0; p < 2; ++p) {
    const int idx = tid + p * 256;              // 0..511
    const int nn = idx >> 3;
    const int cb = (idx & 7) * 8;
    u16 tmp[8];
#pragma unroll
    for (int j = 0; j < 8; ++j) tmp[j] = ls[cb + j][nn];
    *(uint4*)(xnT + ((size_t)b * NSP + n0 + nn) * CCH + c0 + cb) = *(uint4*)tmp;
  }
}

// ------------------------------------------------ MFMA GEMM, BK=64, coalesced staging
// C[b][m][n] = sum_c A[m][c]*Bt[b][n][c]; A bf16 MxK(K=256), Bt bf16 NxK.
// LDS granule G (16B = 8 bf16) holds (row=G>>3, kc=(G&7)^(row&7)). Staging lane
// order = G order -> 128B contiguous global segments. Epilogue via LDS.
template <int OUTF32>
__global__ __launch_bounds__(256) void gemm_mfma(const u16* __restrict__ A,
                                                 const u16* __restrict__ Bt,
                                                 const float* __restrict__ bias,
                                                 void* __restrict__ Cm, int M) {
  __shared__ __align__(16) u16 smem[17408];     // 34816 B: staging 32KB / C-tile epi
  const int tid = threadIdx.x, wave = tid >> 6, lane = tid & 63;
  const int n0 = blockIdx.x * 128, m0 = blockIdx.y * 128, bz = blockIdx.z;
  const u16* Bb = Bt + (size_t)bz * (size_t)NSP * CCH;

  const int lrow = lane >> 3;                   // 0..7: row within 8-row group
  const int kcl  = ((lane & 7) ^ lrow) * 8;     // swizzled k element offset
  const u16* pA[4]; const u16* pB[4];
#pragma unroll
  for (int j = 0; j < 4; ++j) {
    const int row = j * 32 + wave * 8 + lrow;
    pA[j] = A  + (size_t)(m0 + row) * CCH + kcl;
    pB[j] = Bb + (size_t)(n0 + row) * CCH + kcl;
  }
  u16* lA = smem;                               // 1024 granules (16KB)
  u16* lB = smem + 8192;                        // 1024 granules (16KB)

  const int wm = wave >> 1, wn = wave & 1;
  f32x4 acc[4][4];
#pragma unroll
  for (int i = 0; i < 4; ++i)
#pragma unroll
    for (int j = 0; j < 4; ++j) acc[i][j] = (f32x4){0.f, 0.f, 0.f, 0.f};

  for (int it = 0; it < 4; ++it) {              // K = 256, BK = 64
#pragma unroll
    for (int j = 0; j < 4; ++j) {
      __builtin_amdgcn_global_load_lds(GLB(pA[j]), LDSP(lA + (j * 256 + wave * 64) * 8), 16, 0, 0);
      __builtin_amdgcn_global_load_lds(GLB(pB[j]), LDSP(lB + (j * 256 + wave * 64) * 8), 16, 0, 0);
      pA[j] += 64; pB[j] += 64;
    }
    __syncthreads();
#pragma unroll
    for (int w = 0; w < 2; ++w) {               // two 32-k windows
      const int kcf = w * 4 + (lane >> 4);
      short8 af[4], bfr[4];
#pragma unroll
      for (int mt = 0; mt < 4; ++mt) {
        const int row = wm * 64 + mt * 16 + (lane & 15);
        af[mt] = *(const short8*)&lA[(row * 8 + (kcf ^ (row & 7))) * 8];
      }
#pragma unroll
      for (int nt = 0; nt < 4; ++nt) {
        const int row = wn * 64 + nt * 16 + (lane & 15);
        bfr[nt] = *(const short8*)&lB[(row * 8 + (kcf ^ (row & 7))) * 8];
      }
#pragma unroll
      for (int mt = 0; mt < 4; ++mt)
#pragma unroll
        for (int nt = 0; nt < 4; ++nt)
          acc[mt][nt] = __builtin_amdgcn_mfma_f32_16x16x32_bf16(af[mt], bfr[nt], acc[mt][nt], 0, 0, 0);
    }
    __syncthreads();
  }

  // epilogue: C/D frag col=lane&15, row=(lane>>4)*4+reg
  if (!OUTF32) {
    u16* cl = smem;                             // [128][136] u16 (34816 B)
#pragma unroll
    for (int mt = 0; mt < 4; ++mt)
#pragma unroll
      for (int nt = 0; nt < 4; ++nt)
#pragma unroll
        for (int r = 0; r < 4; ++r) {
          const int row = wm * 64 + mt * 16 + (lane >> 4) * 4 + r;
          const int col = wn * 64 + nt * 16 + (lane & 15);
          cl[row * 136 + col] = f2bf(acc[mt][nt][r]);
        }
    __syncthreads();
    u16* C = (u16*)Cm + (size_t)bz * M * NSP;
#pragma unroll
    for (int j = 0; j < 8; ++j) {
      const int idx = tid + j * 256;            // 0..2047
      const int row = idx >> 4, chunk = idx & 15;
      *(uint4*)(C + (size_t)(m0 + row) * NSP + n0 + chunk * 8) =
          *(const uint4*)&cl[row * 136 + chunk * 8];
    }
  } else {
    float* clf = (float*)smem;                  // [64][132] fp32 per pass (33792 B)
    float* C = (float*)Cm + (size_t)bz * M * NSP;
#pragma unroll
    for (int pass = 0; pass < 2; ++pass) {
      if (wm == pass) {
#pragma unroll
        for (int mt = 0; mt < 4; ++mt)
#pragma unroll
          for (int nt = 0; nt < 4; ++nt)
#pragma unroll
            for (int r = 0; r < 4; ++r) {
              const int rl = mt * 16 + (lane >> 4) * 4 + r;   // 0..63
              const int col = wn * 64 + nt * 16 + (lane & 15);
              clf[rl * 132 + col] = acc[mt][nt][r] + bias[m0 + pass * 64 + rl];
            }
      }
      __syncthreads();
#pragma unroll
      for (int j = 0; j < 8; ++j) {
        const int idx = tid + j * 256;          // 0..2047
        const int row = idx >> 5, chunk = idx & 31;
        *(float4*)(C + (size_t)(m0 + pass * 64 + row) * NSP + n0 + chunk * 4) =
            *(const float4*)&clf[row * 132 + chunk * 4];
      }
      __syncthreads();
    }
  }
}

// ------------------------------------------------ att4 += sum_n exp(k) v ; l += sum_n exp(k)
// grid (16 n-chunks, 8 h, 16 b). att4 layout per bh: [0,1024) = att[d][e], [1024,1056) = l[d].
__global__ __launch_bounds__(256) void att2_kernel(const u16* __restrict__ qkv,
                                                   float* __restrict__ att4) {
  const int b = blockIdx.z, h = blockIdx.y;
  const int bh = b * 8 + h;
  const int nbase = blockIdx.x * 256;
  const u16* kp = qkv + ((size_t)b * QKV_M + 256 + h * 32) * NSP;
  const u16* vp = qkv + ((size_t)b * QKV_M + 512 + h * 32) * NSP;
  __shared__ __align__(16) float ks[32][132];
  __shared__ __align__(16) float vs[32][132];
  __shared__ float lred[256];
  const int tid = threadIdx.x;
  const int d0 = (tid >> 4) * 2, e0 = (tid & 15) * 2;
  float a00 = 0.f, a01 = 0.f, a10 = 0.f, a11 = 0.f;
  float lacc = 0.f;

  for (int c0 = nbase; c0 < nbase + 256; c0 += 128) {
#pragma unroll
    for (int j = 0; j < 2; ++j) {
      const int idx = tid + j * 256;
      const int row = idx >> 4;
      const int col = (idx & 15) * 8;
      uint4 uk = *(const uint4*)(kp + (size_t)row * NSP + c0 + col);
      uint4 uv = *(const uint4*)(vp + (size_t)row * NSP + c0 + col);
      const u16* ek = (const u16*)&uk; const u16* ev = (const u16*)&uv;
#pragma unroll
      for (int t = 0; t < 8; ++t) {
        ks[row][col + t] = __expf(bf2f(ek[t]));   // no max-sub: |k| small
        vs[row][col + t] = bf2f(ev[t]);
      }
    }
    __syncthreads();
#pragma unroll
    for (int i = 0; i < 128; i += 4) {
      const float4 k0v = *(const float4*)&ks[d0][i];
      const float4 k1v = *(const float4*)&ks[d0 + 1][i];
      const float4 v0v = *(const float4*)&vs[e0][i];
      const float4 v1v = *(const float4*)&vs[e0 + 1][i];
      a00 += k0v.x * v0v.x + k0v.y * v0v.y + k0v.z * v0v.z + k0v.w * v0v.w;
      a01 += k0v.x * v1v.x + k0v.y * v1v.y + k0v.z * v1v.z + k0v.w * v1v.w;
      a10 += k1v.x * v0v.x + k1v.y * v0v.y + k1v.z * v0v.z + k1v.w * v0v.w;
      a11 += k1v.x * v1v.x + k1v.y * v1v.y + k1v.z * v1v.z + k1v.w * v1v.w;
    }
    // row-sum partials of exp(k): thread covers (d = tid>>3, 16 cols)
    {
      const int d = tid >> 3, i0 = (tid & 7) * 16;
      float s16 = 0.f;
#pragma unroll
      for (int i = 0; i < 16; ++i) s16 += ks[d][i0 + i];
      lred[tid] = s16;
    }
    __syncthreads();
    if (tid < 32) {
      float t = 0.f;
#pragma unroll
      for (int j = 0; j < 8; ++j) t += lred[tid * 8 + j];
      lacc += t;
    }
  }
  float* ap = att4 + (size_t)bh * 1056;
  atomicAdd(&ap[(d0 + 0) * 32 + e0 + 0], a00);
  atomicAdd(&ap[(d0 + 0) * 32 + e0 + 1], a01);
  atomicAdd(&ap[(d0 + 1) * 32 + e0 + 0], a10);
  atomicAdd(&ap[(d0 + 1) * 32 + e0 + 1], a11);
  if (tid < 32) atomicAdd(&ap[1024 + tid], lacc);
}

// ------------------------------------------------ out = (att/l)^T @ q -> outT[b][n][c]
__global__ __launch_bounds__(256) void attout_kernel(const u16* __restrict__ qkv,
                                                     const float* __restrict__ att4,
                                                     u16* __restrict__ outT) {
  const int b = blockIdx.z, h = blockIdx.y;
  const int bh = b * 8 + h;
  const int n = blockIdx.x * 256 + threadIdx.x;
  const u16* q = qkv + ((size_t)b * QKV_M + h * 32) * NSP;
  const float* ap = att4 + (size_t)bh * 1056;
  __shared__ float as[32][33];
  for (int i = threadIdx.x; i < 1024; i += 256) {
    const int d = i >> 5;
    as[d][i & 31] = ap[i] / ap[1024 + d];       // fold softmax 1/l_d
  }
  __syncthreads();
  float qv[32];
#pragma unroll
  for (int d = 0; d < 32; ++d) qv[d] = bf2f(q[(size_t)d * NSP + n]);
  u16 ob[32];
#pragma unroll
  for (int e = 0; e < 32; ++e) {
    float acc = 0.f;
#pragma unroll
    for (int d = 0; d < 32; ++d) acc += as[d][e] * qv[d];
    ob[e] = f2bf(acc);
  }
  u16* orow = outT + ((size_t)b * NSP + n) * CCH + h * 32;
#pragma unroll
  for (int j = 0; j < 4; ++j) ((uint4*)orow)[j] = ((const uint4*)ob)[j];
}

// ------------------------------------------------ launch
extern "C" void kernel_launch(void* const* d_in, const int* in_sizes, int n_in,
                              void* d_out, int out_size, void* d_ws, size_t ws_size,
                              hipStream_t stream) {
  const float* x      = (const float*)d_in[0];
  const float* gn_w   = (const float*)d_in[1];
  const float* gn_b   = (const float*)d_in[2];
  const float* w_qkv  = (const float*)d_in[3];
  const float* w_proj = (const float*)d_in[4];
  const float* b_proj = (const float*)d_in[5];
  float* out = (float*)d_out;

  char* ws = (char*)d_ws;
  u16*    xnT   = (u16*)ws;                                 // 32 MiB [b][n][c]; reused as outT
  u16*    qkv   = (u16*)(ws + 33554432ull);                 // 96 MiB [b][768][n]
  float*  att4  = (float*)(ws + 134217728ull);              // 128*1056*4 = 540672 B
  float2* stats = (float2*)(ws + 134758400ull);             // 4 KiB
  u16*    wbf   = (u16*)(ws + 134762496ull);                // 512 KiB
  u16* wq_bf = wbf;
  u16* wp_bf = wbf + 196608;

  convw_kernel<<<256, 256, 0, stream>>>(w_qkv, w_proj, wbf);
  gn_stats<<<512, 256, 0, stream>>>(x, stats, att4);
  gn_apply_t<<<dim3(64, 4, 16), 256, 0, stream>>>(x, gn_w, gn_b, stats, xnT);
  gemm_mfma<0><<<dim3(32, 6, 16), 256, 0, stream>>>(wq_bf, xnT, nullptr, qkv, QKV_M);
  att2_kernel<<<dim3(16, 8, 16), 256, 0, stream>>>(qkv, att4);
  attout_kernel<<<dim3(16, 8, 16), 256, 0, stream>>>(qkv, att4, xnT); // xnT now outT
  gemm_mfma<1><<<dim3(32, 2, 16), 256, 0, stream>>>(wp_bf, xnT, b_proj, out, CCH);
}

// Round 6
// 269.951 us; speedup vs baseline: 1.2128x; 1.2128x over previous
//
#include <hip/hip_runtime.h>
#include <stdint.h>

// x (16,256,64,64) fp32; 32 groups; 8 heads; head dim 32. All I/O fp32.
// Intermediates bf16 in d_ws. GEMMs: bf16 MFMA 16x16x32, BK=64, swizzled
// coalesced global_load_lds staging, LDS-staged coalesced epilogue.
// Softmax folded into att: att = diag(1/l) * sum_n exp(k) v  (no max-sub; |k|<~6).
#define BATCH 16
#define CCH   256
#define NSP   4096
#define QKV_M 768

typedef unsigned short u16;
typedef short  short8 __attribute__((ext_vector_type(8)));   // 8 bf16 (4 VGPRs)
typedef float  f32x4  __attribute__((ext_vector_type(4)));

__device__ __forceinline__ float bf2f(u16 h) {
  union { unsigned int u; float f; } x; x.u = ((unsigned int)h) << 16; return x.f;
}
__device__ __forceinline__ u16 f2bf(float f) {
  union { float f; unsigned int u; } x; x.f = f;
  unsigned int r = 0x7fffu + ((x.u >> 16) & 1u);
  return (u16)((x.u + r) >> 16);
}

#define GLB(p) ((__attribute__((address_space(1))) void*)(p))
#define LDSP(p) ((__attribute__((address_space(3))) void*)(p))

// ------------------------------------------------ weights fp32 -> bf16
__global__ __launch_bounds__(256) void convw_kernel(const float* __restrict__ wq,
                                                    const float* __restrict__ wp,
                                                    u16* __restrict__ dst) {
  const int i = (blockIdx.x * 256 + threadIdx.x) * 4;
  float4 v = (i < 196608) ? *(const float4*)(wq + i)
                          : *(const float4*)(wp + (i - 196608));
  ushort4 o;
  o.x = f2bf(v.x); o.y = f2bf(v.y); o.z = f2bf(v.z); o.w = f2bf(v.w);
  *(ushort4*)(dst + i) = o;
}

// ------------------------------------------------ GroupNorm stats (+ zero att accum)
__global__ __launch_bounds__(256) void gn_stats(const float* __restrict__ x,
                                                float2* __restrict__ stats,
                                                float* __restrict__ att4) {
  const int blk = blockIdx.x;
  const int tid = threadIdx.x;
  // zero att accumulator: 128 heads * 1056 floats = 512 blocks * 264
  {
    float* az = att4 + (size_t)blk * 264;
    for (int i = tid; i < 264; i += 256) az[i] = 0.f;
  }
  const float4* xv = (const float4*)(x + (size_t)blk * 32768);
  float s = 0.f, ss = 0.f;
  for (int i = tid; i < 8192; i += 256) {
    float4 u = xv[i];
    s  += u.x + u.y + u.z + u.w;
    ss += u.x * u.x + u.y * u.y + u.z * u.z + u.w * u.w;
  }
#pragma unroll
  for (int off = 32; off > 0; off >>= 1) {
    s  += __shfl_down(s, off);
    ss += __shfl_down(ss, off);
  }
  __shared__ float red[8];
  const int wave = tid >> 6, lane = tid & 63;
  if (lane == 0) { red[wave * 2] = s; red[wave * 2 + 1] = ss; }
  __syncthreads();
  if (tid == 0) {
    const float S  = red[0] + red[2] + red[4] + red[6];
    const float SS = red[1] + red[3] + red[5] + red[7];
    const float mean = S * (1.f / 32768.f);
    const float var  = SS * (1.f / 32768.f) - mean * mean;
    stats[blk] = make_float2(mean, rsqrtf(var + 1e-5f));
  }
}

// ------------------------------------------------ GN apply + transpose
__global__ __launch_bounds__(256) void gn_apply_t(const float* __restrict__ x,
                                                  const float* __restrict__ gw,
                                                  const float* __restrict__ gb,
                                                  const float2* __restrict__ stats,
                                                  u16* __restrict__ xnT) {
  __shared__ u16 ls[64][72];                    // [c][n], pad 72
  const int b = blockIdx.z, c0 = blockIdx.y * 64, n0 = blockIdx.x * 64;
  const int tid = threadIdx.x;
#pragma unroll
  for (int r = 0; r < 4; ++r) {
    const int cc = (tid >> 4) + r * 16;
    const int nn = (tid & 15) * 4;
    const int c = c0 + cc;
    const float2 st = stats[b * 32 + (c >> 3)];
    const float wv = gw[c] * st.y;
    const float bv = gb[c] - st.x * wv;
    float4 u = *(const float4*)(x + ((size_t)b * CCH + c) * NSP + n0 + nn);
    ushort4 o;
    o.x = f2bf(u.x * wv + bv);
    o.y = f2bf(u.y * wv + bv);
    o.z = f2bf(u.z * wv + bv);
    o.w = f2bf(u.w * wv + bv);
    *(ushort4*)&ls[cc][nn] = o;
  }
  __syncthreads();
#pragma unroll
  for (int p = 0; p < 2; ++p) {
    const int idx = tid + p * 256;              // 0..511
    const int nn = idx >> 3;
    const int cb = (idx & 7) * 8;
    u16 tmp[8];
#pragma unroll
    for (int j = 0; j < 8; ++j) tmp[j] = ls[cb + j][nn];
    *(uint4*)(xnT + ((size_t)b * NSP + n0 + nn) * CCH + c0 + cb) = *(uint4*)tmp;
  }
}

// ------------------------------------------------ MFMA GEMM, BK=64, coalesced staging
// C[b][m][n] = sum_c A[m][c]*Bt[b][n][c]; A bf16 MxK(K=256), Bt bf16 NxK.
template <int OUTF32>
__global__ __launch_bounds__(256) void gemm_mfma(const u16* __restrict__ A,
                                                 const u16* __restrict__ Bt,
                                                 const float* __restrict__ bias,
                                                 void* __restrict__ Cm, int M) {
  __shared__ __align__(16) u16 smem[17408];     // 34816 B: staging 32KB / C-tile epi
  const int tid = threadIdx.x, wave = tid >> 6, lane = tid & 63;
  const int n0 = blockIdx.x * 128, m0 = blockIdx.y * 128, bz = blockIdx.z;
  const u16* Bb = Bt + (size_t)bz * (size_t)NSP * CCH;

  const int lrow = lane >> 3;                   // 0..7: row within 8-row group
  const int kcl  = ((lane & 7) ^ lrow) * 8;     // swizzled k element offset
  const u16* pA[4]; const u16* pB[4];
#pragma unroll
  for (int j = 0; j < 4; ++j) {
    const int row = j * 32 + wave * 8 + lrow;
    pA[j] = A  + (size_t)(m0 + row) * CCH + kcl;
    pB[j] = Bb + (size_t)(n0 + row) * CCH + kcl;
  }
  u16* lA = smem;                               // 1024 granules (16KB)
  u16* lB = smem + 8192;                        // 1024 granules (16KB)

  const int wm = wave >> 1, wn = wave & 1;
  f32x4 acc[4][4];
#pragma unroll
  for (int i = 0; i < 4; ++i)
#pragma unroll
    for (int j = 0; j < 4; ++j) acc[i][j] = (f32x4){0.f, 0.f, 0.f, 0.f};

  for (int it = 0; it < 4; ++it) {              // K = 256, BK = 64
#pragma unroll
    for (int j = 0; j < 4; ++j) {
      __builtin_amdgcn_global_load_lds(GLB(pA[j]), LDSP(lA + (j * 256 + wave * 64) * 8), 16, 0, 0);
      __builtin_amdgcn_global_load_lds(GLB(pB[j]), LDSP(lB + (j * 256 + wave * 64) * 8), 16, 0, 0);
      pA[j] += 64; pB[j] += 64;
    }
    __syncthreads();
#pragma unroll
    for (int w = 0; w < 2; ++w) {               // two 32-k windows
      const int kcf = w * 4 + (lane >> 4);
      short8 af[4], bfr[4];
#pragma unroll
      for (int mt = 0; mt < 4; ++mt) {
        const int row = wm * 64 + mt * 16 + (lane & 15);
        af[mt] = *(const short8*)&lA[(row * 8 + (kcf ^ (row & 7))) * 8];
      }
#pragma unroll
      for (int nt = 0; nt < 4; ++nt) {
        const int row = wn * 64 + nt * 16 + (lane & 15);
        bfr[nt] = *(const short8*)&lB[(row * 8 + (kcf ^ (row & 7))) * 8];
      }
#pragma unroll
      for (int mt = 0; mt < 4; ++mt)
#pragma unroll
        for (int nt = 0; nt < 4; ++nt)
          acc[mt][nt] = __builtin_amdgcn_mfma_f32_16x16x32_bf16(af[mt], bfr[nt], acc[mt][nt], 0, 0, 0);
    }
    __syncthreads();
  }

  // epilogue: C/D frag col=lane&15, row=(lane>>4)*4+reg
  if (!OUTF32) {
    u16* cl = smem;                             // [128][136] u16 (34816 B)
#pragma unroll
    for (int mt = 0; mt < 4; ++mt)
#pragma unroll
      for (int nt = 0; nt < 4; ++nt)
#pragma unroll
        for (int r = 0; r < 4; ++r) {
          const int row = wm * 64 + mt * 16 + (lane >> 4) * 4 + r;
          const int col = wn * 64 + nt * 16 + (lane & 15);
          cl[row * 136 + col] = f2bf(acc[mt][nt][r]);
        }
    __syncthreads();
    u16* C = (u16*)Cm + (size_t)bz * M * NSP;
#pragma unroll
    for (int j = 0; j < 8; ++j) {
      const int idx = tid + j * 256;            // 0..2047
      const int row = idx >> 4, chunk = idx & 15;
      *(uint4*)(C + (size_t)(m0 + row) * NSP + n0 + chunk * 8) =
          *(const uint4*)&cl[row * 136 + chunk * 8];
    }
  } else {
    float* clf = (float*)smem;                  // [64][132] fp32 per pass (33792 B)
    float* C = (float*)Cm + (size_t)bz * M * NSP;
#pragma unroll
    for (int pass = 0; pass < 2; ++pass) {
      if (wm == pass) {
#pragma unroll
        for (int mt = 0; mt < 4; ++mt)
#pragma unroll
          for (int nt = 0; nt < 4; ++nt)
#pragma unroll
            for (int r = 0; r < 4; ++r) {
              const int rl = mt * 16 + (lane >> 4) * 4 + r;   // 0..63
              const int col = wn * 64 + nt * 16 + (lane & 15);
              clf[rl * 132 + col] = acc[mt][nt][r] + bias[m0 + pass * 64 + rl];
            }
      }
      __syncthreads();
#pragma unroll
      for (int j = 0; j < 8; ++j) {
        const int idx = tid + j * 256;          // 0..2047
        const int row = idx >> 5, chunk = idx & 31;
        *(float4*)(C + (size_t)(m0 + pass * 64 + row) * NSP + n0 + chunk * 4) =
            *(const float4*)&clf[row * 132 + chunk * 4];
      }
      __syncthreads();
    }
  }
}

// ------------------------------------------------ att4 += sum_n exp(k) v ; l += sum_n exp(k)
// grid (32 n-chunks of 128, 8 h, 16 b). Per bh: [0,1024)=att[d][e], [1024,1056)=l[d].
// Register-economical: l accumulated in-thread (each thread sweeps its 2 k-rows fully);
// launch_bounds(256,4) caps VGPRs at 128 (R5 post-mortem: 256 VGPR -> 10% occupancy).
__global__ __launch_bounds__(256, 4) void att2_kernel(const u16* __restrict__ qkv,
                                                      float* __restrict__ att4) {
  const int b = blockIdx.z, h = blockIdx.y;
  const int bh = b * 8 + h;
  const int c0 = blockIdx.x * 128;
  const u16* kp = qkv + ((size_t)b * QKV_M + 256 + h * 32) * NSP;
  const u16* vp = qkv + ((size_t)b * QKV_M + 512 + h * 32) * NSP;
  __shared__ __align__(16) float ks[32][132];
  __shared__ __align__(16) float vs[32][132];
  const int tid = threadIdx.x;
  const int d0 = (tid >> 4) * 2, e0 = (tid & 15) * 2;
  float a00 = 0.f, a01 = 0.f, a10 = 0.f, a11 = 0.f;
  float l0 = 0.f, l1 = 0.f;

  // stage 32x128 of k (exp'ed) and v
#pragma unroll
  for (int j = 0; j < 2; ++j) {
    const int idx = tid + j * 256;
    const int row = idx >> 4;
    const int col = (idx & 15) * 8;
    uint4 uk = *(const uint4*)(kp + (size_t)row * NSP + c0 + col);
    uint4 uv = *(const uint4*)(vp + (size_t)row * NSP + c0 + col);
    const u16* ek = (const u16*)&uk; const u16* ev = (const u16*)&uv;
#pragma unroll
    for (int t = 0; t < 8; ++t) {
      ks[row][col + t] = __expf(bf2f(ek[t]));   // no max-sub: |k| small
      vs[row][col + t] = bf2f(ev[t]);
    }
  }
  __syncthreads();
#pragma unroll 8
  for (int i = 0; i < 128; i += 4) {
    const float4 k0v = *(const float4*)&ks[d0][i];
    const float4 k1v = *(const float4*)&ks[d0 + 1][i];
    const float4 v0v = *(const float4*)&vs[e0][i];
    const float4 v1v = *(const float4*)&vs[e0 + 1][i];
    a00 += k0v.x * v0v.x + k0v.y * v0v.y + k0v.z * v0v.z + k0v.w * v0v.w;
    a01 += k0v.x * v1v.x + k0v.y * v1v.y + k0v.z * v1v.z + k0v.w * v1v.w;
    a10 += k1v.x * v0v.x + k1v.y * v0v.y + k1v.z * v0v.z + k1v.w * v0v.w;
    a11 += k1v.x * v1v.x + k1v.y * v1v.y + k1v.z * v1v.z + k1v.w * v1v.w;
    l0  += k0v.x + k0v.y + k0v.z + k0v.w;
    l1  += k1v.x + k1v.y + k1v.z + k1v.w;
  }
  float* ap = att4 + (size_t)bh * 1056;
  atomicAdd(&ap[(d0 + 0) * 32 + e0 + 0], a00);
  atomicAdd(&ap[(d0 + 0) * 32 + e0 + 1], a01);
  atomicAdd(&ap[(d0 + 1) * 32 + e0 + 0], a10);
  atomicAdd(&ap[(d0 + 1) * 32 + e0 + 1], a11);
  if ((tid & 15) == 0) {                        // one lane per d0-group
    atomicAdd(&ap[1024 + d0 + 0], l0);
    atomicAdd(&ap[1024 + d0 + 1], l1);
  }
}

// ------------------------------------------------ out = (att/l)^T @ q -> outT[b][n][c]
__global__ __launch_bounds__(256) void attout_kernel(const u16* __restrict__ qkv,
                                                     const float* __restrict__ att4,
                                                     u16* __restrict__ outT) {
  const int b = blockIdx.z, h = blockIdx.y;
  const int bh = b * 8 + h;
  const int n = blockIdx.x * 256 + threadIdx.x;
  const u16* q = qkv + ((size_t)b * QKV_M + h * 32) * NSP;
  const float* ap = att4 + (size_t)bh * 1056;
  __shared__ float as[32][33];
  for (int i = threadIdx.x; i < 1024; i += 256) {
    const int d = i >> 5;
    as[d][i & 31] = ap[i] / ap[1024 + d];       // fold softmax 1/l_d
  }
  __syncthreads();
  float qv[32];
#pragma unroll
  for (int d = 0; d < 32; ++d) qv[d] = bf2f(q[(size_t)d * NSP + n]);
  u16 ob[32];
#pragma unroll
  for (int e = 0; e < 32; ++e) {
    float acc = 0.f;
#pragma unroll
    for (int d = 0; d < 32; ++d) acc += as[d][e] * qv[d];
    ob[e] = f2bf(acc);
  }
  u16* orow = outT + ((size_t)b * NSP + n) * CCH + h * 32;
#pragma unroll
  for (int j = 0; j < 4; ++j) ((uint4*)orow)[j] = ((const uint4*)ob)[j];
}

// ------------------------------------------------ launch
extern "C" void kernel_launch(void* const* d_in, const int* in_sizes, int n_in,
                              void* d_out, int out_size, void* d_ws, size_t ws_size,
                              hipStream_t stream) {
  const float* x      = (const float*)d_in[0];
  const float* gn_w   = (const float*)d_in[1];
  const float* gn_b   = (const float*)d_in[2];
  const float* w_qkv  = (const float*)d_in[3];
  const float* w_proj = (const float*)d_in[4];
  const float* b_proj = (const float*)d_in[5];
  float* out = (float*)d_out;

  char* ws = (char*)d_ws;
  u16*    xnT   = (u16*)ws;                                 // 32 MiB [b][n][c]; reused as outT
  u16*    qkv   = (u16*)(ws + 33554432ull);                 // 96 MiB [b][768][n]
  float*  att4  = (float*)(ws + 134217728ull);              // 128*1056*4 = 540672 B
  float2* stats = (float2*)(ws + 134758400ull);             // 4 KiB
  u16*    wbf   = (u16*)(ws + 134762496ull);                // 512 KiB
  u16* wq_bf = wbf;
  u16* wp_bf = wbf + 196608;

  convw_kernel<<<256, 256, 0, stream>>>(w_qkv, w_proj, wbf);
  gn_stats<<<512, 256, 0, stream>>>(x, stats, att4);
  gn_apply_t<<<dim3(64, 4, 16), 256, 0, stream>>>(x, gn_w, gn_b, stats, xnT);
  gemm_mfma<0><<<dim3(32, 6, 16), 256, 0, stream>>>(wq_bf, xnT, nullptr, qkv, QKV_M);
  att2_kernel<<<dim3(32, 8, 16), 256, 0, stream>>>(qkv, att4);
  attout_kernel<<<dim3(16, 8, 16), 256, 0, stream>>>(qkv, att4, xnT); // xnT now outT
  gemm_mfma<1><<<dim3(32, 2, 16), 256, 0, stream>>>(wp_bf, xnT, b_proj, out, CCH);
}